// Round 1
// baseline (247.538 us; speedup 1.0000x reference)
//
#include <hip/hip_runtime.h>
#include <hip/hip_bf16.h>

#define B_ 8
#define N_ 2048
#define H_ 8
#define DM_ 512

typedef __bf16 bf16x8 __attribute__((ext_vector_type(8)));
typedef float f32x4 __attribute__((ext_vector_type(4)));
typedef unsigned short us8 __attribute__((ext_vector_type(8)));
typedef unsigned short us4 __attribute__((ext_vector_type(4)));

// All LDS tiles: 64 bf16 per row = 128B row stride, XOR-swizzled 16B granules
// (G4: spreads the 16-row x 4-colgroup b128 fragment reads across all banks).
__device__ __forceinline__ int swz(int row, int byte_in_row) {
  return row * 128 + (byte_in_row ^ ((row & 7) << 4));
}

__device__ __forceinline__ unsigned short f2bf(float x) {
  __bf16 h = (__bf16)x;  // RNE convert
  return __builtin_bit_cast(unsigned short, h);
}

__device__ __forceinline__ f32x4 mfma16(bf16x8 a, bf16x8 b, f32x4 c) {
  return __builtin_amdgcn_mfma_f32_16x16x32_bf16(a, b, c, 0, 0, 0);
}

// Stage a 64x64 f32 tile (row stride src_stride floats) into LDS as bf16,
// swizzled. 256 threads.
__device__ __forceinline__ void stage_f32_tile(const float* __restrict__ src,
                                               int src_stride, char* dst, int t) {
#pragma unroll
  for (int rep = 0; rep < 4; ++rep) {
    int cid = rep * 256 + t;
    int row = cid >> 4, c4 = cid & 15;
    float4 v = *reinterpret_cast<const float4*>(src + (size_t)row * src_stride + c4 * 4);
    us4 o;
    o[0] = f2bf(v.x); o[1] = f2bf(v.y); o[2] = f2bf(v.z); o[3] = f2bf(v.w);
    *reinterpret_cast<us4*>(dst + row * 128 + ((c4 * 8) ^ ((row & 7) << 4))) = o;
  }
}

// Stage a 64x64 bf16 tile (row stride src_stride elements) into LDS, swizzled.
__device__ __forceinline__ void stage_bf16_tile(const unsigned short* __restrict__ src,
                                                int src_stride, char* dst, int t) {
#pragma unroll
  for (int rep = 0; rep < 2; ++rep) {
    int cid = rep * 256 + t;
    int row = cid >> 3, c = cid & 7;
    us8 v = *reinterpret_cast<const us8*>(src + (size_t)row * src_stride + c * 8);
    *reinterpret_cast<us8*>(dst + row * 128 + ((c * 16) ^ ((row & 7) << 4))) = v;
  }
}

// ---------------------------------------------------------------------------
// Kernel A: per-head QKV projection.
//  Q: (x@Wq^T + bq) * 0.125 -> bf16 [b,h,n,e]
//  K: (x@Wk^T + bk)         -> bf16 [b,h,n,e]
//  V: (x@Wv^T + bv)         -> bf16 TRANSPOSED [b,h,e,n]
// Block: 256 thr (4 waves x 16 rows), 64 rows of one (b,h). Grid (32, 64).
// ---------------------------------------------------------------------------
__global__ __launch_bounds__(256, 4) void qkv_kernel(
    const float* __restrict__ x,
    const float* __restrict__ Wq, const float* __restrict__ bq,
    const float* __restrict__ Wk, const float* __restrict__ bk,
    const float* __restrict__ Wv, const float* __restrict__ bv,
    unsigned short* __restrict__ Qw, unsigned short* __restrict__ Kw,
    unsigned short* __restrict__ Vtw) {
  __shared__ __align__(16) char sX[8192];
  __shared__ __align__(16) char sWq[8192];
  __shared__ __align__(16) char sWk[8192];
  __shared__ __align__(16) char sWv[8192];
  __shared__ __align__(16) unsigned short vbuf[64][72];  // transposed V staging

  const int t = threadIdx.x;
  const int bh = blockIdx.y, h = bh & 7, b = bh >> 3;
  const int n0 = blockIdx.x * 64;
  const int lane = t & 63, w = t >> 6, g = lane >> 4, li = lane & 15;

  stage_f32_tile(x + ((size_t)(b * N_ + n0)) * DM_ + h * 64, DM_, sX, t);
  stage_f32_tile(Wq + (size_t)h * 4096, 64, sWq, t);
  stage_f32_tile(Wk + (size_t)h * 4096, 64, sWk, t);
  stage_f32_tile(Wv + (size_t)h * 4096, 64, sWv, t);
  __syncthreads();

  // A-fragments of the x tile (wave w owns rows 16w..16w+15), cached in regs.
  bf16x8 xa0 = *reinterpret_cast<const bf16x8*>(sX + swz(16 * w + li, 16 * g));
  bf16x8 xa1 = *reinterpret_cast<const bf16x8*>(sX + swz(16 * w + li, 64 + 16 * g));

  // ---- Q ----
#pragma unroll
  for (int c = 0; c < 4; ++c) {
    f32x4 a = {0.f, 0.f, 0.f, 0.f};
    bf16x8 b0 = *reinterpret_cast<const bf16x8*>(sWq + swz(c * 16 + li, 16 * g));
    bf16x8 b1 = *reinterpret_cast<const bf16x8*>(sWq + swz(c * 16 + li, 64 + 16 * g));
    a = mfma16(xa0, b0, a);
    a = mfma16(xa1, b1, a);
    float bb = bq[h * 64 + c * 16 + li];
#pragma unroll
    for (int i = 0; i < 4; ++i) {
      int n = n0 + 16 * w + 4 * g + i;
      Qw[((size_t)bh * N_ + n) * 64 + c * 16 + li] = f2bf((a[i] + bb) * 0.125f);
    }
  }
  // ---- K ----
#pragma unroll
  for (int c = 0; c < 4; ++c) {
    f32x4 a = {0.f, 0.f, 0.f, 0.f};
    bf16x8 b0 = *reinterpret_cast<const bf16x8*>(sWk + swz(c * 16 + li, 16 * g));
    bf16x8 b1 = *reinterpret_cast<const bf16x8*>(sWk + swz(c * 16 + li, 64 + 16 * g));
    a = mfma16(xa0, b0, a);
    a = mfma16(xa1, b1, a);
    float bb = bk[h * 64 + c * 16 + li];
#pragma unroll
    for (int i = 0; i < 4; ++i) {
      int n = n0 + 16 * w + 4 * g + i;
      Kw[((size_t)bh * N_ + n) * 64 + c * 16 + li] = f2bf(a[i] + bb);
    }
  }
  // ---- V (transpose in LDS, then coalesced store) ----
#pragma unroll
  for (int c = 0; c < 4; ++c) {
    f32x4 a = {0.f, 0.f, 0.f, 0.f};
    bf16x8 b0 = *reinterpret_cast<const bf16x8*>(sWv + swz(c * 16 + li, 16 * g));
    bf16x8 b1 = *reinterpret_cast<const bf16x8*>(sWv + swz(c * 16 + li, 64 + 16 * g));
    a = mfma16(xa0, b0, a);
    a = mfma16(xa1, b1, a);
    float bb = bv[h * 64 + c * 16 + li];
#pragma unroll
    for (int i = 0; i < 4; ++i) {
      vbuf[c * 16 + li][16 * w + 4 * g + i] = f2bf(a[i] + bb);
    }
  }
  __syncthreads();
#pragma unroll
  for (int rep = 0; rep < 2; ++rep) {
    int cid = rep * 256 + t;
    int e = cid >> 3, c8 = cid & 7;
    us8 v = *reinterpret_cast<const us8*>(&vbuf[e][c8 * 8]);
    *reinterpret_cast<us8*>(Vtw + ((size_t)bh * 64 + e) * N_ + n0 + c8 * 8) = v;
  }
}

// ---------------------------------------------------------------------------
// Kernel B: flash attention. Block: 256 thr (4 waves x 32 q-rows = QT 128).
// K/V tiles of 64 keys staged to swizzled LDS; online softmax in registers;
// P via per-wave LDS round trip (D-layout -> A-layout). Grid (16, 64).
// ---------------------------------------------------------------------------
__global__ __launch_bounds__(256, 2) void attn_kernel(
    const unsigned short* __restrict__ Qw, const unsigned short* __restrict__ Kw,
    const unsigned short* __restrict__ Vtw, unsigned short* __restrict__ AOw) {
  __shared__ __align__(16) char sK[8192];
  __shared__ __align__(16) char sV[8192];
  __shared__ __align__(16) char sP[4][4096];  // per-wave [32][64] bf16

  const int t = threadIdx.x;
  const int bh = blockIdx.y, h = bh & 7, b = bh >> 3;
  const int q0 = blockIdx.x * 128;
  const int lane = t & 63, w = t >> 6, g = lane >> 4, li = lane & 15;

  const size_t hbase = (size_t)bh * N_ * 64;

  // Q fragments straight from global (each element read exactly once).
  bf16x8 qa[2][2];
#pragma unroll
  for (int rt = 0; rt < 2; ++rt)
#pragma unroll
    for (int dt = 0; dt < 2; ++dt)
      qa[rt][dt] = *reinterpret_cast<const bf16x8*>(
          Qw + hbase + (size_t)(q0 + 32 * w + rt * 16 + li) * 64 + dt * 32 + 8 * g);

  f32x4 acc[2][4];
  float m_[2][4], l_[2][4];
#pragma unroll
  for (int rt = 0; rt < 2; ++rt)
#pragma unroll
    for (int c = 0; c < 4; ++c) {
      acc[rt][c][0] = 0.f; acc[rt][c][1] = 0.f; acc[rt][c][2] = 0.f; acc[rt][c][3] = 0.f;
    }
#pragma unroll
  for (int rt = 0; rt < 2; ++rt)
#pragma unroll
    for (int i = 0; i < 4; ++i) {
      m_[rt][i] = -__builtin_inff();
      l_[rt][i] = 0.f;
    }

  for (int kt = 0; kt < 32; ++kt) {
    const int k0 = kt * 64;
    __syncthreads();  // all waves done reading previous K/V tile
    stage_bf16_tile(Kw + hbase + (size_t)k0 * 64, 64, sK, t);
    stage_bf16_tile(Vtw + (size_t)bh * 64 * N_ + k0, N_, sV, t);
    __syncthreads();

    // S = Q K^T (scale folded into Q)
    bf16x8 kf[4][2];
#pragma unroll
    for (int c = 0; c < 4; ++c)
#pragma unroll
      for (int dt = 0; dt < 2; ++dt)
        kf[c][dt] = *reinterpret_cast<const bf16x8*>(sK + swz(c * 16 + li, dt * 64 + 16 * g));

    f32x4 s[2][4];
#pragma unroll
    for (int rt = 0; rt < 2; ++rt)
#pragma unroll
      for (int c = 0; c < 4; ++c) {
        f32x4 z = {0.f, 0.f, 0.f, 0.f};
        z = mfma16(qa[rt][0], kf[c][0], z);
        z = mfma16(qa[rt][1], kf[c][1], z);
        s[rt][c] = z;
      }

    // online softmax (rows 4g+i of the rt sub-tile; reduce over 16-lane group)
#pragma unroll
    for (int rt = 0; rt < 2; ++rt) {
      float tmax[4], tsum[4], al[4];
#pragma unroll
      for (int i = 0; i < 4; ++i)
        tmax[i] = fmaxf(fmaxf(s[rt][0][i], s[rt][1][i]), fmaxf(s[rt][2][i], s[rt][3][i]));
#pragma unroll
      for (int off = 1; off < 16; off <<= 1)
#pragma unroll
        for (int i = 0; i < 4; ++i) tmax[i] = fmaxf(tmax[i], __shfl_xor(tmax[i], off));
#pragma unroll
      for (int i = 0; i < 4; ++i) {
        float mn = fmaxf(m_[rt][i], tmax[i]);
        al[i] = __expf(m_[rt][i] - mn);
        m_[rt][i] = mn;
        tsum[i] = 0.f;
      }
#pragma unroll
      for (int c = 0; c < 4; ++c)
#pragma unroll
        for (int i = 0; i < 4; ++i) {
          float pv = __expf(s[rt][c][i] - m_[rt][i]);
          s[rt][c][i] = pv;
          tsum[i] += pv;
        }
#pragma unroll
      for (int off = 1; off < 16; off <<= 1)
#pragma unroll
        for (int i = 0; i < 4; ++i) tsum[i] += __shfl_xor(tsum[i], off);
#pragma unroll
      for (int i = 0; i < 4; ++i) l_[rt][i] = l_[rt][i] * al[i] + tsum[i];
#pragma unroll
      for (int c2 = 0; c2 < 4; ++c2)
#pragma unroll
        for (int i = 0; i < 4; ++i) acc[rt][c2][i] *= al[i];
      // write P (bf16) to per-wave LDS in [row][col] layout
#pragma unroll
      for (int c = 0; c < 4; ++c)
#pragma unroll
        for (int i = 0; i < 4; ++i)
          *reinterpret_cast<unsigned short*>(
              sP[w] + swz(rt * 16 + 4 * g + i, 2 * (c * 16 + li))) = f2bf(s[rt][c][i]);
    }

    // PV: acc += P V  (wave-local P; no barrier needed)
    bf16x8 vf[4][2];
#pragma unroll
    for (int c2 = 0; c2 < 4; ++c2)
#pragma unroll
      for (int ks = 0; ks < 2; ++ks)
        vf[c2][ks] = *reinterpret_cast<const bf16x8*>(sV + swz(c2 * 16 + li, ks * 64 + 16 * g));
    bf16x8 pf[2][2];
#pragma unroll
    for (int rt = 0; rt < 2; ++rt)
#pragma unroll
      for (int ks = 0; ks < 2; ++ks)
        pf[rt][ks] = *reinterpret_cast<const bf16x8*>(sP[w] + swz(rt * 16 + li, ks * 64 + 16 * g));
#pragma unroll
    for (int rt = 0; rt < 2; ++rt)
#pragma unroll
      for (int c2 = 0; c2 < 4; ++c2) {
        acc[rt][c2] = mfma16(pf[rt][0], vf[c2][0], acc[rt][c2]);
        acc[rt][c2] = mfma16(pf[rt][1], vf[c2][1], acc[rt][c2]);
      }
  }

  // epilogue: normalize and store attn output (bf16, [B,N,DM] with head offset)
#pragma unroll
  for (int rt = 0; rt < 2; ++rt) {
    float inv[4];
#pragma unroll
    for (int i = 0; i < 4; ++i) inv[i] = 1.0f / l_[rt][i];
#pragma unroll
    for (int c2 = 0; c2 < 4; ++c2)
#pragma unroll
      for (int i = 0; i < 4; ++i) {
        int n = q0 + 32 * w + rt * 16 + 4 * g + i;
        AOw[((size_t)b * N_ + n) * DM_ + h * 64 + c2 * 16 + li] =
            f2bf(acc[rt][c2][i] * inv[i]);
      }
  }
}

// ---------------------------------------------------------------------------
// Kernel C: output projection  out = AO @ Wp^T + bp  (f32 out).
// Block: 256 thr, out tile 64 rows x 64 cols, K-loop over DM. Grid (256, 8).
// ---------------------------------------------------------------------------
__global__ __launch_bounds__(256, 4) void proj_kernel(
    const unsigned short* __restrict__ AOw, const float* __restrict__ Wp,
    const float* __restrict__ bp, float* __restrict__ out) {
  __shared__ __align__(16) char sA[8192];
  __shared__ __align__(16) char sB[8192];

  const int t = threadIdx.x;
  const int r0 = blockIdx.x * 64;  // rows of the [B*N, DM] matrix
  const int i0 = blockIdx.y * 64;  // output column tile
  const int lane = t & 63, w = t >> 6, g = lane >> 4, li = lane & 15;

  f32x4 acc[4];
#pragma unroll
  for (int c = 0; c < 4; ++c) {
    acc[c][0] = 0.f; acc[c][1] = 0.f; acc[c][2] = 0.f; acc[c][3] = 0.f;
  }

  for (int jt = 0; jt < 8; ++jt) {
    __syncthreads();
    stage_bf16_tile(AOw + (size_t)r0 * DM_ + jt * 64, DM_, sA, t);
    stage_f32_tile(Wp + (size_t)i0 * DM_ + jt * 64, DM_, sB, t);
    __syncthreads();

    bf16x8 a0 = *reinterpret_cast<const bf16x8*>(sA + swz(16 * w + li, 16 * g));
    bf16x8 a1 = *reinterpret_cast<const bf16x8*>(sA + swz(16 * w + li, 64 + 16 * g));
#pragma unroll
    for (int c = 0; c < 4; ++c) {
      bf16x8 b0 = *reinterpret_cast<const bf16x8*>(sB + swz(c * 16 + li, 16 * g));
      bf16x8 b1 = *reinterpret_cast<const bf16x8*>(sB + swz(c * 16 + li, 64 + 16 * g));
      acc[c] = mfma16(a0, b0, acc[c]);
      acc[c] = mfma16(a1, b1, acc[c]);
    }
  }

#pragma unroll
  for (int c = 0; c < 4; ++c) {
    float bb = bp[i0 + c * 16 + li];
#pragma unroll
    for (int i = 0; i < 4; ++i)
      out[(size_t)(r0 + 16 * w + 4 * g + i) * DM_ + i0 + c * 16 + li] = acc[c][i] + bb;
  }
}

extern "C" void kernel_launch(void* const* d_in, const int* in_sizes, int n_in,
                              void* d_out, int out_size, void* d_ws, size_t ws_size,
                              hipStream_t stream) {
  const float* x  = (const float*)d_in[0];
  const float* Wq = (const float*)d_in[1];
  const float* bq = (const float*)d_in[2];
  const float* Wk = (const float*)d_in[3];
  const float* bk = (const float*)d_in[4];
  const float* Wv = (const float*)d_in[5];
  const float* bv = (const float*)d_in[6];
  const float* Wp = (const float*)d_in[7];
  const float* bp = (const float*)d_in[8];
  float* out = (float*)d_out;

  // workspace: Q, K, Vt, AO — each B*H*N*64 bf16 = 16 MiB; total 64 MiB
  const size_t seg = (size_t)B_ * H_ * N_ * 64;  // elements
  unsigned short* Qw  = (unsigned short*)d_ws;
  unsigned short* Kw  = Qw + seg;
  unsigned short* Vtw = Kw + seg;
  unsigned short* AOw = Vtw + seg;

  qkv_kernel<<<dim3(32, 64), 256, 0, stream>>>(x, Wq, bq, Wk, bk, Wv, bv, Qw, Kw, Vtw);
  attn_kernel<<<dim3(16, 64), 256, 0, stream>>>(Qw, Kw, Vtw, AOw);
  proj_kernel<<<dim3(256, 8), 256, 0, stream>>>(AOw, Wp, bp, out);
}

// Round 2
// 154.185 us; speedup vs baseline: 1.6055x; 1.6055x over previous
//
#include <hip/hip_runtime.h>
#include <hip/hip_bf16.h>

#define B_ 8
#define N_ 2048
#define H_ 8
#define DM_ 512
#define NT_ 32  // N_/64 K-tiles

typedef __bf16 bf16x8 __attribute__((ext_vector_type(8)));
typedef float f32x4 __attribute__((ext_vector_type(4)));
typedef float f32x16 __attribute__((ext_vector_type(16)));
typedef unsigned short us8 __attribute__((ext_vector_type(8)));
typedef unsigned short us4 __attribute__((ext_vector_type(4)));
typedef unsigned int u32x4 __attribute__((ext_vector_type(4)));

// fold 1/sqrt(64) * log2(e) into Q so softmax runs in exp2 domain
#define QSCALE 0.1803368801111204f

// LDS tiles: 64 bf16 per row = 128B row stride, XOR-swizzled 16B granules.
__device__ __forceinline__ int swz(int row, int byte_in_row) {
  return row * 128 + (byte_in_row ^ ((row & 7) << 4));
}

__device__ __forceinline__ unsigned short f2bf(float x) {
  __bf16 h = (__bf16)x;
  return __builtin_bit_cast(unsigned short, h);
}

__device__ __forceinline__ float fexp2(float x) {
#if __has_builtin(__builtin_amdgcn_exp2f)
  return __builtin_amdgcn_exp2f(x);
#else
  return exp2f(x);
#endif
}

__device__ __forceinline__ unsigned cvtpk(float a, float b) {
  unsigned r;
  asm("v_cvt_pk_bf16_f32 %0, %1, %2" : "=v"(r) : "v"(a), "v"(b));
  return r;
}

__device__ __forceinline__ f32x4 mfma16(bf16x8 a, bf16x8 b, f32x4 c) {
  return __builtin_amdgcn_mfma_f32_16x16x32_bf16(a, b, c, 0, 0, 0);
}
__device__ __forceinline__ f32x16 mfma32(bf16x8 a, bf16x8 b, f32x16 c) {
  return __builtin_amdgcn_mfma_f32_32x32x16_bf16(a, b, c, 0, 0, 0);
}

// global -> LDS direct (16B/lane). LDS dest is wave-uniform base + lane*16.
#define GLL16(g, l)                                                        \
  __builtin_amdgcn_global_load_lds(                                        \
      (const __attribute__((address_space(1))) unsigned int*)(g),          \
      (__attribute__((address_space(3))) unsigned int*)(unsigned long)(l), \
      16, 0, 0)

// Stage a 64x64 f32 tile into LDS as bf16, swizzled. 256 threads.
__device__ __forceinline__ void stage_f32_tile(const float* __restrict__ src,
                                               int src_stride, char* dst, int t) {
#pragma unroll
  for (int rep = 0; rep < 4; ++rep) {
    int cid = rep * 256 + t;
    int row = cid >> 4, c4 = cid & 15;
    float4 v = *reinterpret_cast<const float4*>(src + (size_t)row * src_stride + c4 * 4);
    us4 o;
    o[0] = f2bf(v.x); o[1] = f2bf(v.y); o[2] = f2bf(v.z); o[3] = f2bf(v.w);
    *reinterpret_cast<us4*>(dst + row * 128 + ((c4 * 8) ^ ((row & 7) << 4))) = o;
  }
}

__device__ __forceinline__ void stage_bf16_tile(const unsigned short* __restrict__ src,
                                                int src_stride, char* dst, int t) {
#pragma unroll
  for (int rep = 0; rep < 2; ++rep) {
    int cid = rep * 256 + t;
    int row = cid >> 3, c = cid & 7;
    us8 v = *reinterpret_cast<const us8*>(src + (size_t)row * src_stride + c * 8);
    *reinterpret_cast<us8*>(dst + row * 128 + ((c * 16) ^ ((row & 7) << 4))) = v;
  }
}

// ---------------------------------------------------------------------------
// Kernel A: per-head QKV projection (Q scaled by 1/8*log2e; V stored transposed)
// ---------------------------------------------------------------------------
__global__ __launch_bounds__(256, 4) void qkv_kernel(
    const float* __restrict__ x,
    const float* __restrict__ Wq, const float* __restrict__ bq,
    const float* __restrict__ Wk, const float* __restrict__ bk,
    const float* __restrict__ Wv, const float* __restrict__ bv,
    unsigned short* __restrict__ Qw, unsigned short* __restrict__ Kw,
    unsigned short* __restrict__ Vtw) {
  __shared__ __align__(16) char sX[8192];
  __shared__ __align__(16) char sWq[8192];
  __shared__ __align__(16) char sWk[8192];
  __shared__ __align__(16) char sWv[8192];
  __shared__ __align__(16) unsigned short vbuf[64][72];

  const int t = threadIdx.x;
  const int bh = blockIdx.y, h = bh & 7, b = bh >> 3;
  const int n0 = blockIdx.x * 64;
  const int lane = t & 63, w = t >> 6, g = lane >> 4, li = lane & 15;

  stage_f32_tile(x + ((size_t)(b * N_ + n0)) * DM_ + h * 64, DM_, sX, t);
  stage_f32_tile(Wq + (size_t)h * 4096, 64, sWq, t);
  stage_f32_tile(Wk + (size_t)h * 4096, 64, sWk, t);
  stage_f32_tile(Wv + (size_t)h * 4096, 64, sWv, t);
  __syncthreads();

  bf16x8 xa0 = *reinterpret_cast<const bf16x8*>(sX + swz(16 * w + li, 16 * g));
  bf16x8 xa1 = *reinterpret_cast<const bf16x8*>(sX + swz(16 * w + li, 64 + 16 * g));

#pragma unroll
  for (int c = 0; c < 4; ++c) {
    f32x4 a = {0.f, 0.f, 0.f, 0.f};
    bf16x8 b0 = *reinterpret_cast<const bf16x8*>(sWq + swz(c * 16 + li, 16 * g));
    bf16x8 b1 = *reinterpret_cast<const bf16x8*>(sWq + swz(c * 16 + li, 64 + 16 * g));
    a = mfma16(xa0, b0, a);
    a = mfma16(xa1, b1, a);
    float bb = bq[h * 64 + c * 16 + li];
#pragma unroll
    for (int i = 0; i < 4; ++i) {
      int n = n0 + 16 * w + 4 * g + i;
      Qw[((size_t)bh * N_ + n) * 64 + c * 16 + li] = f2bf((a[i] + bb) * QSCALE);
    }
  }
#pragma unroll
  for (int c = 0; c < 4; ++c) {
    f32x4 a = {0.f, 0.f, 0.f, 0.f};
    bf16x8 b0 = *reinterpret_cast<const bf16x8*>(sWk + swz(c * 16 + li, 16 * g));
    bf16x8 b1 = *reinterpret_cast<const bf16x8*>(sWk + swz(c * 16 + li, 64 + 16 * g));
    a = mfma16(xa0, b0, a);
    a = mfma16(xa1, b1, a);
    float bb = bk[h * 64 + c * 16 + li];
#pragma unroll
    for (int i = 0; i < 4; ++i) {
      int n = n0 + 16 * w + 4 * g + i;
      Kw[((size_t)bh * N_ + n) * 64 + c * 16 + li] = f2bf(a[i] + bb);
    }
  }
#pragma unroll
  for (int c = 0; c < 4; ++c) {
    f32x4 a = {0.f, 0.f, 0.f, 0.f};
    bf16x8 b0 = *reinterpret_cast<const bf16x8*>(sWv + swz(c * 16 + li, 16 * g));
    bf16x8 b1 = *reinterpret_cast<const bf16x8*>(sWv + swz(c * 16 + li, 64 + 16 * g));
    a = mfma16(xa0, b0, a);
    a = mfma16(xa1, b1, a);
    float bb = bv[h * 64 + c * 16 + li];
#pragma unroll
    for (int i = 0; i < 4; ++i) {
      vbuf[c * 16 + li][16 * w + 4 * g + i] = f2bf(a[i] + bb);
    }
  }
  __syncthreads();
#pragma unroll
  for (int rep = 0; rep < 2; ++rep) {
    int cid = rep * 256 + t;
    int e = cid >> 3, c8 = cid & 7;
    us8 v = *reinterpret_cast<const us8*>(&vbuf[e][c8 * 8]);
    *reinterpret_cast<us8*>(Vtw + ((size_t)bh * 64 + e) * N_ + n0 + c8 * 8) = v;
  }
}

// ---------------------------------------------------------------------------
// Kernel B: flash attention, swapped-QK^T 32x32 structure.
// 256 thr (4 waves x 32 q-rows = QT 128). Grid: 1024 blocks (XCD-swizzled).
// S^T = K*Q^T (each lane owns one q-row), in-register softmax (exp2 domain,
// defer-max), T12 repack to PV B-fragments, O^T = V^T * P^T.
// ---------------------------------------------------------------------------
__global__ __launch_bounds__(256) void attn_kernel(
    const unsigned short* __restrict__ Qw, const unsigned short* __restrict__ Kw,
    const unsigned short* __restrict__ Vtw, unsigned short* __restrict__ AOw) {
  __shared__ __align__(16) char sKV[2][2][8192];  // [buf][K|V][64x64 bf16]

  const int t = threadIdx.x;
  const int lane = t & 63, w = t >> 6;
  const int lo = lane & 31, hi = lane >> 5;
  const bool hb = hi != 0;

  // XCD swizzle: all 16 q-blocks of a (b,h) land on one XCD.
  const int bid = blockIdx.x;
  const int work = (bid & 7) * 128 + (bid >> 3);
  const int bh = work >> 4;
  const int qb = work & 15;
  const int h = bh & 7, b = bh >> 3;
  const int q0 = qb * 128;

  const size_t hbase = (size_t)bh * N_ * 64;

  // staging addresses: pre-swizzled global source, linear LDS dest
  const int srow = 8 * w + (lane >> 3);
  const int sg = (lane & 7) ^ ((lane >> 3) & 7);
  const unsigned short* gK = Kw + hbase + (size_t)srow * 64 + 8 * sg;
  const unsigned short* gV = Vtw + (size_t)(bh * 64 + srow) * N_ + 8 * sg;

  auto STAGE = [&](int kt, int buf) {
    const unsigned short* k1 = gK + (size_t)kt * 4096;
    const unsigned short* v1 = gV + (size_t)kt * 64;
    GLL16(k1, sKV[buf][0] + w * 1024);
    GLL16(k1 + 2048, sKV[buf][0] + 4096 + w * 1024);
    GLL16(v1, sKV[buf][1] + w * 1024);
    GLL16(v1 + (size_t)32 * N_, sKV[buf][1] + 4096 + w * 1024);
  };

  STAGE(0, 0);

  // Q fragments (B-operand of S^T): lane holds Q[q0+32w+lo][16dd+8hi+j]
  bf16x8 qf[4];
  {
    const unsigned short* qptr =
        Qw + hbase + (size_t)(q0 + 32 * w + lo) * 64 + 8 * hi;
#pragma unroll
    for (int dd = 0; dd < 4; ++dd)
      qf[dd] = *reinterpret_cast<const bf16x8*>(qptr + 16 * dd);
  }

  f32x16 o0 = {}, o1 = {};
  float m = -__builtin_inff(), l = 0.f;

  __syncthreads();

  auto TILE = [&](int kt, int cb) {
    if (kt + 1 < NT_) STAGE(kt + 1, cb ^ 1);
    const char* bK = sKV[cb][0];
    const char* bV = sKV[cb][1];

    // K fragments (A-operand): lane holds K[k0+32ks+lo][16dd+8hi+j]
    bf16x8 kf[2][4];
#pragma unroll
    for (int ks = 0; ks < 2; ++ks)
#pragma unroll
      for (int dd = 0; dd < 4; ++dd)
        kf[ks][dd] = *reinterpret_cast<const bf16x8*>(
            bK + swz(32 * ks + lo, 32 * dd + 16 * hi));

    f32x16 s0 = {}, s1 = {};
    __builtin_amdgcn_s_setprio(1);
#pragma unroll
    for (int dd = 0; dd < 4; ++dd) {
      s0 = mfma32(kf[0][dd], qf[dd], s0);
      s1 = mfma32(kf[1][dd], qf[dd], s1);
    }
    __builtin_amdgcn_s_setprio(0);
    // lane holds S^T[k = 32ks + (r&3)+8*(r>>2)+4hi][q = lo], exp2 domain

    // row max (this lane's 32 values + partner's 32)
    float pm;
    {
      float a0 = fmaxf(s0[0], s0[1]), a1 = fmaxf(s0[2], s0[3]);
      float a2 = fmaxf(s0[4], s0[5]), a3 = fmaxf(s0[6], s0[7]);
      float a4 = fmaxf(s0[8], s0[9]), a5 = fmaxf(s0[10], s0[11]);
      float a6 = fmaxf(s0[12], s0[13]), a7 = fmaxf(s0[14], s0[15]);
      float b0 = fmaxf(s1[0], s1[1]), b1 = fmaxf(s1[2], s1[3]);
      float b2 = fmaxf(s1[4], s1[5]), b3 = fmaxf(s1[6], s1[7]);
      float b4 = fmaxf(s1[8], s1[9]), b5 = fmaxf(s1[10], s1[11]);
      float b6 = fmaxf(s1[12], s1[13]), b7 = fmaxf(s1[14], s1[15]);
      a0 = fmaxf(fmaxf(a0, a1), fmaxf(a2, a3));
      a4 = fmaxf(fmaxf(a4, a5), fmaxf(a6, a7));
      b0 = fmaxf(fmaxf(b0, b1), fmaxf(b2, b3));
      b4 = fmaxf(fmaxf(b4, b5), fmaxf(b6, b7));
      pm = fmaxf(fmaxf(a0, a4), fmaxf(b0, b4));
    }
    pm = fmaxf(pm, __shfl_xor(pm, 32));

    // defer-max (T13): rescale only when tile max exceeds running ref by >8
    if (!__all(pm <= m + 8.0f)) {
      float mn = fmaxf(m, pm);
      float al = fexp2(m - mn);
      l *= al;
#pragma unroll
      for (int r = 0; r < 16; ++r) { o0[r] *= al; o1[r] *= al; }
      m = mn;
    }

    // P = exp2(S - m), row-sum
    float ts0 = 0.f, ts1 = 0.f, ts2 = 0.f, ts3 = 0.f;
#pragma unroll
    for (int r = 0; r < 16; r += 4) {
      s0[r + 0] = fexp2(s0[r + 0] - m); ts0 += s0[r + 0];
      s0[r + 1] = fexp2(s0[r + 1] - m); ts1 += s0[r + 1];
      s0[r + 2] = fexp2(s0[r + 2] - m); ts2 += s0[r + 2];
      s0[r + 3] = fexp2(s0[r + 3] - m); ts3 += s0[r + 3];
      s1[r + 0] = fexp2(s1[r + 0] - m); ts0 += s1[r + 0];
      s1[r + 1] = fexp2(s1[r + 1] - m); ts1 += s1[r + 1];
      s1[r + 2] = fexp2(s1[r + 2] - m); ts2 += s1[r + 2];
      s1[r + 3] = fexp2(s1[r + 3] - m); ts3 += s1[r + 3];
    }
    float ts = (ts0 + ts1) + (ts2 + ts3);
    ts += __shfl_xor(ts, 32);
    l += ts;

    // T12 repack: pack quads to bf16, exchange halves, build PV B-fragments.
    // quad qi of sX holds k = 32*kss + {4qi..4qi+3} + 4hi(owner)
    unsigned pl0[4], ph0[4], pl1[4], ph1[4];
#pragma unroll
    for (int qi = 0; qi < 4; ++qi) {
      pl0[qi] = cvtpk(s0[4 * qi + 0], s0[4 * qi + 1]);
      ph0[qi] = cvtpk(s0[4 * qi + 2], s0[4 * qi + 3]);
      pl1[qi] = cvtpk(s1[4 * qi + 0], s1[4 * qi + 1]);
      ph1[qi] = cvtpk(s1[4 * qi + 2], s1[4 * qi + 3]);
    }
    bf16x8 pf[4];
#pragma unroll
    for (int ks = 0; ks < 4; ++ks) {
      const int p = ks & 1;
      unsigned k0l, k0h, k1l, k1h;
      if (ks < 2) { k0l = pl0[2 * p]; k0h = ph0[2 * p]; k1l = pl0[2 * p + 1]; k1h = ph0[2 * p + 1]; }
      else        { k0l = pl1[2 * p]; k0h = ph1[2 * p]; k1l = pl1[2 * p + 1]; k1h = ph1[2 * p + 1]; }
      unsigned sl = hb ? k0l : k1l, sh = hb ? k0h : k1h;  // send quad 2p+(hi^1)
      unsigned rl = __shfl_xor(sl, 32), rh = __shfl_xor(sh, 32);
      unsigned Al = hb ? rl : k0l, Ah = hb ? rh : k0h;  // j0..3 (from hi'=0)
      unsigned Bl = hb ? k1l : rl, Bh = hb ? k1h : rh;  // j4..7 (from hi'=1)
      u32x4 words = {Al, Ah, Bl, Bh};
      pf[ks] = __builtin_bit_cast(bf16x8, words);
    }

    // PV: O^T += V^T * P^T
    __builtin_amdgcn_s_setprio(1);
#pragma unroll
    for (int ks = 0; ks < 4; ++ks) {
      bf16x8 v0 = *reinterpret_cast<const bf16x8*>(bV + swz(lo, 32 * ks + 16 * hi));
      bf16x8 v1 = *reinterpret_cast<const bf16x8*>(bV + swz(32 + lo, 32 * ks + 16 * hi));
      o0 = mfma32(v0, pf[ks], o0);
      o1 = mfma32(v1, pf[ks], o1);
    }
    __builtin_amdgcn_s_setprio(0);
    __syncthreads();
  };

#pragma unroll 1
  for (int kt2 = 0; kt2 < NT_ / 2; ++kt2) {
    TILE(2 * kt2, 0);
    TILE(2 * kt2 + 1, 1);
  }

  // epilogue: normalize, store O^T (lane's col q = lo; e = (r&3)+8(r>>2)+4hi)
  const float invl = 1.0f / l;
  unsigned short* aoptr =
      AOw + ((size_t)(b * N_) + q0 + 32 * w + lo) * DM_ + h * 64 + 4 * hi;
#pragma unroll
  for (int qi = 0; qi < 4; ++qi) {
    us4 pk;
#pragma unroll
    for (int rr = 0; rr < 4; ++rr) pk[rr] = f2bf(o0[4 * qi + rr] * invl);
    *reinterpret_cast<us4*>(aoptr + 8 * qi) = pk;
  }
#pragma unroll
  for (int qi = 0; qi < 4; ++qi) {
    us4 pk;
#pragma unroll
    for (int rr = 0; rr < 4; ++rr) pk[rr] = f2bf(o1[4 * qi + rr] * invl);
    *reinterpret_cast<us4*>(aoptr + 32 + 8 * qi) = pk;
  }
}

// ---------------------------------------------------------------------------
// Kernel C: output projection  out = AO @ Wp^T + bp  (f32 out).
// ---------------------------------------------------------------------------
__global__ __launch_bounds__(256, 4) void proj_kernel(
    const unsigned short* __restrict__ AOw, const float* __restrict__ Wp,
    const float* __restrict__ bp, float* __restrict__ out) {
  __shared__ __align__(16) char sA[8192];
  __shared__ __align__(16) char sB[8192];

  const int t = threadIdx.x;
  const int r0 = blockIdx.x * 64;
  const int i0 = blockIdx.y * 64;
  const int lane = t & 63, w = t >> 6, g = lane >> 4, li = lane & 15;

  f32x4 acc[4];
#pragma unroll
  for (int c = 0; c < 4; ++c) {
    acc[c][0] = 0.f; acc[c][1] = 0.f; acc[c][2] = 0.f; acc[c][3] = 0.f;
  }

  for (int jt = 0; jt < 8; ++jt) {
    __syncthreads();
    stage_bf16_tile(AOw + (size_t)r0 * DM_ + jt * 64, DM_, sA, t);
    stage_f32_tile(Wp + (size_t)i0 * DM_ + jt * 64, DM_, sB, t);
    __syncthreads();

    bf16x8 a0 = *reinterpret_cast<const bf16x8*>(sA + swz(16 * w + li, 16 * g));
    bf16x8 a1 = *reinterpret_cast<const bf16x8*>(sA + swz(16 * w + li, 64 + 16 * g));
#pragma unroll
    for (int c = 0; c < 4; ++c) {
      bf16x8 b0 = *reinterpret_cast<const bf16x8*>(sB + swz(c * 16 + li, 16 * g));
      bf16x8 b1 = *reinterpret_cast<const bf16x8*>(sB + swz(c * 16 + li, 64 + 16 * g));
      acc[c] = mfma16(a0, b0, acc[c]);
      acc[c] = mfma16(a1, b1, acc[c]);
    }
  }

#pragma unroll
  for (int c = 0; c < 4; ++c) {
    float bb = bp[i0 + c * 16 + li];
#pragma unroll
    for (int i = 0; i < 4; ++i)
      out[(size_t)(r0 + 16 * w + 4 * g + i) * DM_ + i0 + c * 16 + li] = acc[c][i] + bb;
  }
}

extern "C" void kernel_launch(void* const* d_in, const int* in_sizes, int n_in,
                              void* d_out, int out_size, void* d_ws, size_t ws_size,
                              hipStream_t stream) {
  const float* x  = (const float*)d_in[0];
  const float* Wq = (const float*)d_in[1];
  const float* bq = (const float*)d_in[2];
  const float* Wk = (const float*)d_in[3];
  const float* bk = (const float*)d_in[4];
  const float* Wv = (const float*)d_in[5];
  const float* bv = (const float*)d_in[6];
  const float* Wp = (const float*)d_in[7];
  const float* bp = (const float*)d_in[8];
  float* out = (float*)d_out;

  const size_t seg = (size_t)B_ * H_ * N_ * 64;  // elements
  unsigned short* Qw  = (unsigned short*)d_ws;
  unsigned short* Kw  = Qw + seg;
  unsigned short* Vtw = Kw + seg;
  unsigned short* AOw = Vtw + seg;

  qkv_kernel<<<dim3(32, 64), 256, 0, stream>>>(x, Wq, bq, Wk, bk, Wv, bv, Qw, Kw, Vtw);
  attn_kernel<<<dim3(1024), 256, 0, stream>>>(Qw, Kw, Vtw, AOw);
  proj_kernel<<<dim3(256, 8), 256, 0, stream>>>(AOw, Wp, bp, out);
}

// Round 3
// 148.396 us; speedup vs baseline: 1.6681x; 1.0390x over previous
//
#include <hip/hip_runtime.h>
#include <hip/hip_bf16.h>

#define B_ 8
#define N_ 2048
#define H_ 8
#define DM_ 512
#define NT_ 32  // N_/64 K-tiles

typedef __bf16 bf16x8 __attribute__((ext_vector_type(8)));
typedef float f32x4 __attribute__((ext_vector_type(4)));
typedef float f32x16 __attribute__((ext_vector_type(16)));
typedef unsigned short us8 __attribute__((ext_vector_type(8)));
typedef unsigned short us4 __attribute__((ext_vector_type(4)));
typedef unsigned int u32x4 __attribute__((ext_vector_type(4)));

// fold 1/sqrt(64) * log2(e) into Q so softmax runs in exp2 domain
#define QSCALE 0.1803368801111204f

// LDS tiles (qkv/proj only): 64 bf16 per row = 128B stride, XOR-swizzled.
__device__ __forceinline__ int swz(int row, int byte_in_row) {
  return row * 128 + (byte_in_row ^ ((row & 7) << 4));
}

__device__ __forceinline__ unsigned short f2bf(float x) {
  __bf16 h = (__bf16)x;
  return __builtin_bit_cast(unsigned short, h);
}

__device__ __forceinline__ float fexp2(float x) {
#if __has_builtin(__builtin_amdgcn_exp2f)
  return __builtin_amdgcn_exp2f(x);
#else
  return exp2f(x);
#endif
}

__device__ __forceinline__ unsigned cvtpk(float a, float b) {
  unsigned r;
  asm("v_cvt_pk_bf16_f32 %0, %1, %2" : "=v"(r) : "v"(a), "v"(b));
  return r;
}

__device__ __forceinline__ f32x4 mfma16(bf16x8 a, bf16x8 b, f32x4 c) {
  return __builtin_amdgcn_mfma_f32_16x16x32_bf16(a, b, c, 0, 0, 0);
}
__device__ __forceinline__ f32x16 mfma32(bf16x8 a, bf16x8 b, f32x16 c) {
  return __builtin_amdgcn_mfma_f32_32x32x16_bf16(a, b, c, 0, 0, 0);
}

__device__ __forceinline__ bf16x8 ldg8(const unsigned short* p) {
  return *reinterpret_cast<const bf16x8*>(p);
}

// Stage a 64x64 f32 tile into LDS as bf16, swizzled. 256 threads.
__device__ __forceinline__ void stage_f32_tile(const float* __restrict__ src,
                                               int src_stride, char* dst, int t) {
#pragma unroll
  for (int rep = 0; rep < 4; ++rep) {
    int cid = rep * 256 + t;
    int row = cid >> 4, c4 = cid & 15;
    float4 v = *reinterpret_cast<const float4*>(src + (size_t)row * src_stride + c4 * 4);
    us4 o;
    o[0] = f2bf(v.x); o[1] = f2bf(v.y); o[2] = f2bf(v.z); o[3] = f2bf(v.w);
    *reinterpret_cast<us4*>(dst + row * 128 + ((c4 * 8) ^ ((row & 7) << 4))) = o;
  }
}

__device__ __forceinline__ void stage_bf16_tile(const unsigned short* __restrict__ src,
                                                int src_stride, char* dst, int t) {
#pragma unroll
  for (int rep = 0; rep < 2; ++rep) {
    int cid = rep * 256 + t;
    int row = cid >> 3, c = cid & 7;
    us8 v = *reinterpret_cast<const us8*>(src + (size_t)row * src_stride + c * 8);
    *reinterpret_cast<us8*>(dst + row * 128 + ((c * 16) ^ ((row & 7) << 4))) = v;
  }
}

// ---------------------------------------------------------------------------
// Kernel A: per-head QKV projection, storing Q/K/V^T in MFMA-FRAGMENT order:
//  Qf/Kf element (n,e): (n>>5)*2048 + (e>>4)*512 + ((e>>3)&1)*256 + (n&31)*8 + (e&7)
//  Vf element (n=k, e=d): (n>>6)*4096 + (e>>5)*2048 + ((n>>4)&3)*512
//                          + ((n>>3)&1)*256 + (e&31)*8 + (n&7)
// so the attention kernel loads fragments as contiguous lane*16B dwordx4.
// ---------------------------------------------------------------------------
__global__ __launch_bounds__(256, 4) void qkv_kernel(
    const float* __restrict__ x,
    const float* __restrict__ Wq, const float* __restrict__ bq,
    const float* __restrict__ Wk, const float* __restrict__ bk,
    const float* __restrict__ Wv, const float* __restrict__ bv,
    unsigned short* __restrict__ Qf, unsigned short* __restrict__ Kf,
    unsigned short* __restrict__ Vf) {
  __shared__ __align__(16) char sX[8192];
  __shared__ __align__(16) char sWq[8192];
  __shared__ __align__(16) char sWk[8192];
  __shared__ __align__(16) char sWv[8192];

  const int t = threadIdx.x;
  const int bh = blockIdx.y, h = bh & 7, b = bh >> 3;
  const int n0 = blockIdx.x * 64;
  const int lane = t & 63, w = t >> 6, g = lane >> 4, li = lane & 15;

  stage_f32_tile(x + ((size_t)(b * N_ + n0)) * DM_ + h * 64, DM_, sX, t);
  stage_f32_tile(Wq + (size_t)h * 4096, 64, sWq, t);
  stage_f32_tile(Wk + (size_t)h * 4096, 64, sWk, t);
  stage_f32_tile(Wv + (size_t)h * 4096, 64, sWv, t);
  __syncthreads();

  bf16x8 xa0 = *reinterpret_cast<const bf16x8*>(sX + swz(16 * w + li, 16 * g));
  bf16x8 xa1 = *reinterpret_cast<const bf16x8*>(sX + swz(16 * w + li, 64 + 16 * g));

  const size_t seg = (size_t)N_ * 64;
  // Q/K fragment store base for this lane (c and (4g+i) added per element):
  const int qkbase =
      ((n0 >> 5) + (w >> 1)) * 2048 + (li >> 3) * 256 + (w & 1) * 128 + (li & 7);
  // V fragment store base (c parts added per element; i gives +1 each):
  const int vbase =
      (n0 >> 6) * 4096 + w * 512 + (g >> 1) * 256 + 4 * (g & 1) + li * 8;

  unsigned short* Qs = Qf + (size_t)bh * seg;
  unsigned short* Ks = Kf + (size_t)bh * seg;
  unsigned short* Vs = Vf + (size_t)bh * seg;

#pragma unroll
  for (int c = 0; c < 4; ++c) {
    f32x4 a = {0.f, 0.f, 0.f, 0.f};
    bf16x8 b0 = *reinterpret_cast<const bf16x8*>(sWq + swz(c * 16 + li, 16 * g));
    bf16x8 b1 = *reinterpret_cast<const bf16x8*>(sWq + swz(c * 16 + li, 64 + 16 * g));
    a = mfma16(xa0, b0, a);
    a = mfma16(xa1, b1, a);
    float bb = bq[h * 64 + c * 16 + li];
#pragma unroll
    for (int i = 0; i < 4; ++i)
      Qs[qkbase + c * 512 + (4 * g + i) * 8] = f2bf((a[i] + bb) * QSCALE);
  }
#pragma unroll
  for (int c = 0; c < 4; ++c) {
    f32x4 a = {0.f, 0.f, 0.f, 0.f};
    bf16x8 b0 = *reinterpret_cast<const bf16x8*>(sWk + swz(c * 16 + li, 16 * g));
    bf16x8 b1 = *reinterpret_cast<const bf16x8*>(sWk + swz(c * 16 + li, 64 + 16 * g));
    a = mfma16(xa0, b0, a);
    a = mfma16(xa1, b1, a);
    float bb = bk[h * 64 + c * 16 + li];
#pragma unroll
    for (int i = 0; i < 4; ++i)
      Ks[qkbase + c * 512 + (4 * g + i) * 8] = f2bf(a[i] + bb);
  }
#pragma unroll
  for (int c = 0; c < 4; ++c) {
    f32x4 a = {0.f, 0.f, 0.f, 0.f};
    bf16x8 b0 = *reinterpret_cast<const bf16x8*>(sWv + swz(c * 16 + li, 16 * g));
    bf16x8 b1 = *reinterpret_cast<const bf16x8*>(sWv + swz(c * 16 + li, 64 + 16 * g));
    a = mfma16(xa0, b0, a);
    a = mfma16(xa1, b1, a);
    float bb = bv[h * 64 + c * 16 + li];
    us4 pk;
#pragma unroll
    for (int i = 0; i < 4; ++i) pk[i] = f2bf(a[i] + bb);
    *reinterpret_cast<us4*>(Vs + vbase + (c >> 1) * 2048 + (c & 1) * 128) = pk;
  }
}

// ---------------------------------------------------------------------------
// Kernel B: flash attention — NO LDS, NO BARRIERS. Fragments load straight
// from the fragment-ordered workspace (coalesced dwordx4 -> regs; L1 serves
// the 4 waves of a block re-reading the same K/V tile). Swapped QK^T 32x32,
// in-register softmax (exp2, defer-max), T12 repack, O^T = V^T * P^T.
// ---------------------------------------------------------------------------
__global__ __launch_bounds__(256, 3) void attn_kernel(
    const unsigned short* __restrict__ Qf, const unsigned short* __restrict__ Kf,
    const unsigned short* __restrict__ Vf, unsigned short* __restrict__ AOw) {
  const int t = threadIdx.x;
  const int lane = t & 63, w = t >> 6;
  const int lo = lane & 31, hi = lane >> 5;
  const bool hb = hi != 0;

  // XCD swizzle: all 16 q-chunks of a (b,h) land on one XCD.
  const int bid = blockIdx.x;
  const int work = (bid & 7) * 128 + (bid >> 3);
  const int bh = work >> 4;
  const int qb = (work & 15) * 4 + w;  // this wave's 32-row q-block
  const int h = bh & 7, b = bh >> 3;

  const size_t seg = (size_t)N_ * 64;
  const unsigned short* qp = Qf + (size_t)bh * seg + qb * 2048 + lane * 8;
  const unsigned short* kp = Kf + (size_t)bh * seg + lane * 8;
  const unsigned short* vp = Vf + (size_t)bh * seg + lane * 8;

  bf16x8 qf[4];
#pragma unroll
  for (int dd = 0; dd < 4; ++dd) qf[dd] = ldg8(qp + dd * 512);

  f32x16 o0 = {}, o1 = {};
  float m = -__builtin_inff(), l = 0.f;

#pragma unroll 1
  for (int kt = 0; kt < NT_; ++kt) {
    const unsigned short* kpt = kp + kt * 4096;
    const unsigned short* vpt = vp + kt * 4096;
    // issue all 16 fragment loads; compiler inserts counted vmcnt waits
    bf16x8 kf0[4], kf1[4], vf0[4], vf1[4];
#pragma unroll
    for (int dd = 0; dd < 4; ++dd) {
      kf0[dd] = ldg8(kpt + dd * 512);
      kf1[dd] = ldg8(kpt + 2048 + dd * 512);
    }
#pragma unroll
    for (int ks = 0; ks < 4; ++ks) {
      vf0[ks] = ldg8(vpt + ks * 512);
      vf1[ks] = ldg8(vpt + 2048 + ks * 512);
    }

    f32x16 s0 = {}, s1 = {};
    __builtin_amdgcn_s_setprio(1);
#pragma unroll
    for (int dd = 0; dd < 4; ++dd) {
      s0 = mfma32(kf0[dd], qf[dd], s0);
      s1 = mfma32(kf1[dd], qf[dd], s1);
    }
    __builtin_amdgcn_s_setprio(0);
    // lane holds S^T[k = 32ks + (r&3)+8*(r>>2)+4hi][q = lo], exp2 domain

    // row max (this lane's 32 values + partner's 32)
    float pm;
    {
      float a0 = fmaxf(s0[0], s0[1]), a1 = fmaxf(s0[2], s0[3]);
      float a2 = fmaxf(s0[4], s0[5]), a3 = fmaxf(s0[6], s0[7]);
      float a4 = fmaxf(s0[8], s0[9]), a5 = fmaxf(s0[10], s0[11]);
      float a6 = fmaxf(s0[12], s0[13]), a7 = fmaxf(s0[14], s0[15]);
      float b0 = fmaxf(s1[0], s1[1]), b1 = fmaxf(s1[2], s1[3]);
      float b2 = fmaxf(s1[4], s1[5]), b3 = fmaxf(s1[6], s1[7]);
      float b4 = fmaxf(s1[8], s1[9]), b5 = fmaxf(s1[10], s1[11]);
      float b6 = fmaxf(s1[12], s1[13]), b7 = fmaxf(s1[14], s1[15]);
      a0 = fmaxf(fmaxf(a0, a1), fmaxf(a2, a3));
      a4 = fmaxf(fmaxf(a4, a5), fmaxf(a6, a7));
      b0 = fmaxf(fmaxf(b0, b1), fmaxf(b2, b3));
      b4 = fmaxf(fmaxf(b4, b5), fmaxf(b6, b7));
      pm = fmaxf(fmaxf(a0, a4), fmaxf(b0, b4));
    }
    pm = fmaxf(pm, __shfl_xor(pm, 32));

    // defer-max (T13): rescale only when tile max exceeds running ref by >8
    if (!__all(pm <= m + 8.0f)) {
      float mn = fmaxf(m, pm);
      float al = fexp2(m - mn);
      l *= al;
#pragma unroll
      for (int r = 0; r < 16; ++r) { o0[r] *= al; o1[r] *= al; }
      m = mn;
    }

    // P = exp2(S - m), row-sum
    float ts0 = 0.f, ts1 = 0.f, ts2 = 0.f, ts3 = 0.f;
#pragma unroll
    for (int r = 0; r < 16; r += 4) {
      s0[r + 0] = fexp2(s0[r + 0] - m); ts0 += s0[r + 0];
      s0[r + 1] = fexp2(s0[r + 1] - m); ts1 += s0[r + 1];
      s0[r + 2] = fexp2(s0[r + 2] - m); ts2 += s0[r + 2];
      s0[r + 3] = fexp2(s0[r + 3] - m); ts3 += s0[r + 3];
      s1[r + 0] = fexp2(s1[r + 0] - m); ts0 += s1[r + 0];
      s1[r + 1] = fexp2(s1[r + 1] - m); ts1 += s1[r + 1];
      s1[r + 2] = fexp2(s1[r + 2] - m); ts2 += s1[r + 2];
      s1[r + 3] = fexp2(s1[r + 3] - m); ts3 += s1[r + 3];
    }
    float ts = (ts0 + ts1) + (ts2 + ts3);
    ts += __shfl_xor(ts, 32);
    l += ts;

    // T12 repack: pack quads to bf16, exchange halves, build PV B-fragments.
    unsigned pl0[4], ph0[4], pl1[4], ph1[4];
#pragma unroll
    for (int qi = 0; qi < 4; ++qi) {
      pl0[qi] = cvtpk(s0[4 * qi + 0], s0[4 * qi + 1]);
      ph0[qi] = cvtpk(s0[4 * qi + 2], s0[4 * qi + 3]);
      pl1[qi] = cvtpk(s1[4 * qi + 0], s1[4 * qi + 1]);
      ph1[qi] = cvtpk(s1[4 * qi + 2], s1[4 * qi + 3]);
    }
    bf16x8 pf[4];
#pragma unroll
    for (int ks = 0; ks < 4; ++ks) {
      const int p = ks & 1;
      unsigned k0l, k0h, k1l, k1h;
      if (ks < 2) { k0l = pl0[2 * p]; k0h = ph0[2 * p]; k1l = pl0[2 * p + 1]; k1h = ph0[2 * p + 1]; }
      else        { k0l = pl1[2 * p]; k0h = ph1[2 * p]; k1l = pl1[2 * p + 1]; k1h = ph1[2 * p + 1]; }
      unsigned sl = hb ? k0l : k1l, sh = hb ? k0h : k1h;  // send quad 2p+(hi^1)
      unsigned rl = __shfl_xor(sl, 32), rh = __shfl_xor(sh, 32);
      unsigned Al = hb ? rl : k0l, Ah = hb ? rh : k0h;  // j0..3 (from hi'=0)
      unsigned Bl = hb ? k1l : rl, Bh = hb ? k1h : rh;  // j4..7 (from hi'=1)
      u32x4 words = {Al, Ah, Bl, Bh};
      pf[ks] = __builtin_bit_cast(bf16x8, words);
    }

    // PV: O^T += V^T * P^T
    __builtin_amdgcn_s_setprio(1);
#pragma unroll
    for (int ks = 0; ks < 4; ++ks) {
      o0 = mfma32(vf0[ks], pf[ks], o0);
      o1 = mfma32(vf1[ks], pf[ks], o1);
    }
    __builtin_amdgcn_s_setprio(0);
  }

  // epilogue: normalize, store O^T (lane's col q = lo; e = (r&3)+8(r>>2)+4hi)
  const float invl = 1.0f / l;
  unsigned short* aoptr =
      AOw + ((size_t)(b * N_) + qb * 32 + lo) * DM_ + h * 64 + 4 * hi;
#pragma unroll
  for (int qi = 0; qi < 4; ++qi) {
    us4 pk;
#pragma unroll
    for (int rr = 0; rr < 4; ++rr) pk[rr] = f2bf(o0[4 * qi + rr] * invl);
    *reinterpret_cast<us4*>(aoptr + 8 * qi) = pk;
  }
#pragma unroll
  for (int qi = 0; qi < 4; ++qi) {
    us4 pk;
#pragma unroll
    for (int rr = 0; rr < 4; ++rr) pk[rr] = f2bf(o1[4 * qi + rr] * invl);
    *reinterpret_cast<us4*>(aoptr + 32 + 8 * qi) = pk;
  }
}

// ---------------------------------------------------------------------------
// Kernel C: output projection  out = AO @ Wp^T + bp  (f32 out).
// ---------------------------------------------------------------------------
__global__ __launch_bounds__(256, 4) void proj_kernel(
    const unsigned short* __restrict__ AOw, const float* __restrict__ Wp,
    const float* __restrict__ bp, float* __restrict__ out) {
  __shared__ __align__(16) char sA[8192];
  __shared__ __align__(16) char sB[8192];

  const int t = threadIdx.x;
  const int r0 = blockIdx.x * 64;
  const int i0 = blockIdx.y * 64;
  const int lane = t & 63, w = t >> 6, g = lane >> 4, li = lane & 15;

  f32x4 acc[4];
#pragma unroll
  for (int c = 0; c < 4; ++c) {
    acc[c][0] = 0.f; acc[c][1] = 0.f; acc[c][2] = 0.f; acc[c][3] = 0.f;
  }

  for (int jt = 0; jt < 8; ++jt) {
    __syncthreads();
    stage_bf16_tile(AOw + (size_t)r0 * DM_ + jt * 64, DM_, sA, t);
    stage_f32_tile(Wp + (size_t)i0 * DM_ + jt * 64, DM_, sB, t);
    __syncthreads();

    bf16x8 a0 = *reinterpret_cast<const bf16x8*>(sA + swz(16 * w + li, 16 * g));
    bf16x8 a1 = *reinterpret_cast<const bf16x8*>(sA + swz(16 * w + li, 64 + 16 * g));
#pragma unroll
    for (int c = 0; c < 4; ++c) {
      bf16x8 b0 = *reinterpret_cast<const bf16x8*>(sB + swz(c * 16 + li, 16 * g));
      bf16x8 b1 = *reinterpret_cast<const bf16x8*>(sB + swz(c * 16 + li, 64 + 16 * g));
      acc[c] = mfma16(a0, b0, acc[c]);
      acc[c] = mfma16(a1, b1, acc[c]);
    }
  }

#pragma unroll
  for (int c = 0; c < 4; ++c) {
    float bb = bp[i0 + c * 16 + li];
#pragma unroll
    for (int i = 0; i < 4; ++i)
      out[(size_t)(r0 + 16 * w + 4 * g + i) * DM_ + i0 + c * 16 + li] = acc[c][i] + bb;
  }
}

extern "C" void kernel_launch(void* const* d_in, const int* in_sizes, int n_in,
                              void* d_out, int out_size, void* d_ws, size_t ws_size,
                              hipStream_t stream) {
  const float* x  = (const float*)d_in[0];
  const float* Wq = (const float*)d_in[1];
  const float* bq = (const float*)d_in[2];
  const float* Wk = (const float*)d_in[3];
  const float* bk = (const float*)d_in[4];
  const float* Wv = (const float*)d_in[5];
  const float* bv = (const float*)d_in[6];
  const float* Wp = (const float*)d_in[7];
  const float* bp = (const float*)d_in[8];
  float* out = (float*)d_out;

  const size_t seg = (size_t)B_ * H_ * N_ * 64;  // elements
  unsigned short* Qf  = (unsigned short*)d_ws;
  unsigned short* Kf  = Qf + seg;
  unsigned short* Vf  = Kf + seg;
  unsigned short* AOw = Vf + seg;

  qkv_kernel<<<dim3(32, 64), 256, 0, stream>>>(x, Wq, bq, Wk, bk, Wv, bv, Qf, Kf, Vf);
  attn_kernel<<<dim3(1024), 256, 0, stream>>>(Qf, Kf, Vf, AOw);
  proj_kernel<<<dim3(256, 8), 256, 0, stream>>>(AOw, Wp, bp, out);
}